// Round 1
// baseline (6866.427 us; speedup 1.0000x reference)
//
#include <hip/hip_runtime.h>
#include <cstdint>

#define BX   32
#define NN   1000
#define FF   16
#define TT   48          // HIST + FC
#define HIST 24
#define FC   24
#define HID  64
#define DEG  16
#define GCIN 18          // F + 2
#define BN   (BX*NN)     // 32000 nodes

__device__ __forceinline__ float sigf(float x)  { return 1.0f/(1.0f+__expf(-x)); }
__device__ __forceinline__ float tanhf_(float x){ return 2.0f/(1.0f+__expf(-2.0f*x)) - 1.0f; }

// ---------------- encoder step: gather + GraphConv + GRU + out-proj ----------------
// block = 256 threads = 4 waves = 2 groups of 64 nodes; each group served by 2 waves
// (j-halves 0..31 / 32..63). grid = 250 blocks -> 32000 nodes.
__global__ __launch_bounds__(256, 1) void enc_step(
    const float* __restrict__ X, const float* __restrict__ y,
    const int*   __restrict__ esrc, const float* __restrict__ ew,
    const float* __restrict__ W_rel, const float* __restrict__ b_rel,
    const float* __restrict__ W_root,
    const float* __restrict__ Wih, const float* __restrict__ Whh,
    const float* __restrict__ bih, const float* __restrict__ bhh,
    const float* __restrict__ Wout, const float* __restrict__ bout,
    const float* __restrict__ h_in, float* __restrict__ h_out,
    const float* __restrict__ xn_in, float* __restrict__ xn_out,
    int t)
{
    __shared__ float cl[HID][128];   // conv exchange (transposed: conflict-free)
    __shared__ float xs[2][128];     // xn partial sums

    const int tid  = threadIdx.x;
    const int lane = tid & 63;
    const int w    = tid >> 6;                 // 0..3
    const int grp  = w >> 1;                   // node group in block
    int jh         = w & 1;                    // j-half
    jh = __builtin_amdgcn_readfirstlane(jh);   // force wave-uniform -> s_load weights
    const int nl   = grp*64 + lane;            // 0..127
    const int node = blockIdx.x*128 + nl;      // < 32000
    const int b    = node / NN;
    const int nloc = node - b*NN;

    const float* Xt = X + (size_t)(b*TT + t)*NN*FF;
    const float* yt = y + (size_t)(b*TT + t)*NN;

    // ---- own features xg = [xn, y, X] ----
    float xg[GCIN];
    xg[0] = xn_in[node];
    xg[1] = yt[nloc];
    {
        const float4* xr = (const float4*)(Xt + nloc*FF);
        #pragma unroll
        for (int q=0;q<4;q++){ float4 v = xr[q];
            xg[2+4*q]=v.x; xg[3+4*q]=v.y; xg[4+4*q]=v.z; xg[5+4*q]=v.w; }
    }

    // ---- gather: 16 contiguous in-edges per node, no atomics ----
    float agg[GCIN];
    #pragma unroll
    for (int i=0;i<GCIN;i++) agg[i]=0.f;
    {
        const int e0 = node*DEG;
        const int4*   sv = (const int4*)  (esrc + e0);
        const float4* wv = (const float4*)(ew   + e0);
        #pragma unroll
        for (int q=0;q<4;q++){
            int4   s4 = sv[q];
            float4 w4 = wv[q];
            const int   ss[4] = {s4.x, s4.y, s4.z, s4.w};
            const float ww[4] = {w4.x, w4.y, w4.z, w4.w};
            #pragma unroll
            for (int i=0;i<4;i++){
                const int s = ss[i]; const float wgt = ww[i];
                const int sl = s - b*NN;
                agg[0] += wgt * xn_in[s];
                agg[1] += wgt * yt[sl];
                const float4* sr = (const float4*)(Xt + sl*FF);
                #pragma unroll
                for (int q2=0;q2<4;q2++){
                    float4 v = sr[q2];
                    agg[2+4*q2] += wgt*v.x; agg[3+4*q2] += wgt*v.y;
                    agg[4+4*q2] += wgt*v.z; agg[5+4*q2] += wgt*v.w;
                }
            }
        }
    }

    // ---- GraphConv half (32 outputs per wave) -> LDS ----
    {
        float c[32];
        #pragma unroll
        for (int j=0;j<32;j++) c[j] = b_rel[jh*32+j];
        #pragma unroll
        for (int k=0;k<GCIN;k++){
            const float* wr = W_rel  + k*HID + jh*32;
            const float* wo = W_root + k*HID + jh*32;
            #pragma unroll
            for (int j=0;j<32;j++) c[j] += agg[k]*wr[j] + xg[k]*wo[j];
        }
        #pragma unroll
        for (int j=0;j<32;j++) cl[jh*32+j][nl] = sigf(c[j]);
    }
    __syncthreads();

    float conv[HID];
    #pragma unroll
    for (int k=0;k<HID;k++) conv[k] = cl[k][nl];

    float h[HID];
    #pragma unroll
    for (int k=0;k<HID;k++) h[k] = h_in[(size_t)k*BN + node];

    // ---- GRU gates, 32 outputs per wave (dynamic j-loop, static inner dots) ----
    float xacc = 0.f;
    for (int j=0;j<32;j++){
        const int jj = jh*32 + j;
        const float* wr_r = Wih + (size_t) jj      *82;
        const float* wr_z = Wih + (size_t)(jj+ 64) *82;
        const float* wr_n = Wih + (size_t)(jj+128) *82;
        float ir = bih[jj], iz = bih[64+jj], in2 = bih[128+jj];
        #pragma unroll
        for (int k=0;k<GCIN;k++){
            const float xv = xg[k];
            ir += xv*wr_r[k]; iz += xv*wr_z[k]; in2 += xv*wr_n[k];
        }
        #pragma unroll
        for (int k=0;k<HID;k++){
            const float xv = conv[k];
            ir += xv*wr_r[GCIN+k]; iz += xv*wr_z[GCIN+k]; in2 += xv*wr_n[GCIN+k];
        }
        const float* wh_r = Whh + (size_t) jj      *HID;
        const float* wh_z = Whh + (size_t)(jj+ 64) *HID;
        const float* wh_n = Whh + (size_t)(jj+128) *HID;
        float hr = bhh[jj], hz = bhh[64+jj], hn2 = bhh[128+jj];
        #pragma unroll
        for (int k=0;k<HID;k++){
            const float hv = h[k];
            hr += hv*wh_r[k]; hz += hv*wh_z[k]; hn2 += hv*wh_n[k];
        }
        const float r = sigf(ir+hr);
        const float z = sigf(iz+hz);
        const float n = tanhf_(in2 + r*hn2);
        const float hold = h_in[(size_t)jj*BN + node];   // == h[jj] (L1 hit; avoids scratch)
        const float hp = (1.f - z)*n + z*hold;
        h_out[(size_t)jj*BN + node] = hp;
        xacc += hp * Wout[jj];
    }

    xs[jh][nl] = xacc;
    __syncthreads();
    if (jh == 0)
        xn_out[node] = xs[0][nl] + xs[1][nl] + bout[0];
}

// ---------------- decoder step: in-proj + GRU + out-proj ----------------
__global__ __launch_bounds__(256, 1) void dec_step(
    const float* __restrict__ X,
    const float* __restrict__ Win, const float* __restrict__ bin,
    const float* __restrict__ Wih, const float* __restrict__ Whh,
    const float* __restrict__ bih, const float* __restrict__ bhh,
    const float* __restrict__ Wout, const float* __restrict__ bout,
    const float* __restrict__ h_in, float* __restrict__ h_out,
    const float* __restrict__ xn_in, float* __restrict__ xn_out,
    float* __restrict__ out, int t)
{
    __shared__ float xs[2][128];

    const int tid  = threadIdx.x;
    const int lane = tid & 63;
    const int w    = tid >> 6;
    const int grp  = w >> 1;
    int jh         = w & 1;
    jh = __builtin_amdgcn_readfirstlane(jh);
    const int nl   = grp*64 + lane;
    const int node = blockIdx.x*128 + nl;
    const int b    = node / NN;
    const int nloc = node - b*NN;

    const float* Xt = X + (size_t)(b*TT + HIST + t)*NN*FF;

    float x4[4];
    x4[0] = xn_in[node];
    x4[1] = Xt[nloc*FF + 13];
    x4[2] = Xt[nloc*FF + 14];
    x4[3] = Xt[nloc*FF + 15];

    // xin = x4 @ Win(4x64) + bin  (computed fully by each wave; cheap)
    float xin[HID];
    #pragma unroll
    for (int j=0;j<HID;j++)
        xin[j] = bin[j] + x4[0]*Win[j] + x4[1]*Win[64+j] + x4[2]*Win[128+j] + x4[3]*Win[192+j];

    float h[HID];
    #pragma unroll
    for (int k=0;k<HID;k++) h[k] = h_in[(size_t)k*BN + node];

    float xacc = 0.f;
    for (int j=0;j<32;j++){
        const int jj = jh*32 + j;
        const float* wr_r = Wih + (size_t) jj      *HID;
        const float* wr_z = Wih + (size_t)(jj+ 64) *HID;
        const float* wr_n = Wih + (size_t)(jj+128) *HID;
        float ir = bih[jj], iz = bih[64+jj], in2 = bih[128+jj];
        #pragma unroll
        for (int k=0;k<HID;k++){
            const float xv = xin[k];
            ir += xv*wr_r[k]; iz += xv*wr_z[k]; in2 += xv*wr_n[k];
        }
        const float* wh_r = Whh + (size_t) jj      *HID;
        const float* wh_z = Whh + (size_t)(jj+ 64) *HID;
        const float* wh_n = Whh + (size_t)(jj+128) *HID;
        float hr = bhh[jj], hz = bhh[64+jj], hn2 = bhh[128+jj];
        #pragma unroll
        for (int k=0;k<HID;k++){
            const float hv = h[k];
            hr += hv*wh_r[k]; hz += hv*wh_z[k]; hn2 += hv*wh_n[k];
        }
        const float r = sigf(ir+hr);
        const float z = sigf(iz+hz);
        const float n = tanhf_(in2 + r*hn2);
        const float hold = h_in[(size_t)jj*BN + node];
        const float hp = (1.f - z)*n + z*hold;
        h_out[(size_t)jj*BN + node] = hp;
        xacc += hp * Wout[jj];
    }

    xs[jh][nl] = xacc;
    __syncthreads();
    if (jh == 0){
        const float v = xs[0][nl] + xs[1][nl] + bout[0];
        xn_out[node] = v;
        out[(size_t)(b*FC + t)*NN + nloc] = v;
    }
}

extern "C" void kernel_launch(void* const* d_in, const int* in_sizes, int n_in,
                              void* d_out, int out_size, void* d_ws, size_t ws_size,
                              hipStream_t stream)
{
    const float* X     = (const float*)d_in[0];
    const float* y     = (const float*)d_in[1];
    const int*   ei    = (const int*)  d_in[2];   // [2][E]; row 0 = src
    const float* ew    = (const float*)d_in[3];
    const float* W_rel = (const float*)d_in[4];
    const float* b_rel = (const float*)d_in[5];
    const float* W_root= (const float*)d_in[6];
    const float* eWih  = (const float*)d_in[7];
    const float* eWhh  = (const float*)d_in[8];
    const float* ebih  = (const float*)d_in[9];
    const float* ebhh  = (const float*)d_in[10];
    const float* eWout = (const float*)d_in[11];
    const float* ebout = (const float*)d_in[12];
    const float* dWin  = (const float*)d_in[13];
    const float* dbin  = (const float*)d_in[14];
    const float* dWih  = (const float*)d_in[15];
    const float* dWhh  = (const float*)d_in[16];
    const float* dbih  = (const float*)d_in[17];
    const float* dbhh  = (const float*)d_in[18];
    const float* dWout = (const float*)d_in[19];
    const float* dbout = (const float*)d_in[20];
    float* out = (float*)d_out;

    // workspace: ping-pong h (2 x 8.192 MB) + ping-pong xn (2 x 128 KB)
    float* h0 = (float*)d_ws;
    float* h1 = h0 + (size_t)BN*HID;
    float* x0 = h1 + (size_t)BN*HID;
    float* x1 = x0 + BN;

    hipMemsetAsync(h0, 0, (size_t)BN*HID*sizeof(float), stream);
    hipMemsetAsync(x0, 0, (size_t)BN*sizeof(float), stream);

    const int* esrc = ei;  // first E entries

    float* hin = h0; float* hout = h1;
    float* xin = x0; float* xout = x1;

    for (int t=0; t<HIST; t++){
        enc_step<<<250, 256, 0, stream>>>(X, y, esrc, ew, W_rel, b_rel, W_root,
                                          eWih, eWhh, ebih, ebhh, eWout, ebout,
                                          hin, hout, xin, xout, t);
        float* tmp;
        tmp = hin; hin = hout; hout = tmp;
        tmp = xin; xin = xout; xout = tmp;
    }
    for (int t=0; t<FC; t++){
        dec_step<<<250, 256, 0, stream>>>(X, dWin, dbin, dWih, dWhh, dbih, dbhh,
                                          dWout, dbout, hin, hout, xin, xout, out, t);
        float* tmp;
        tmp = hin; hin = hout; hout = tmp;
        tmp = xin; xin = xout; xout = tmp;
    }
}

// Round 3
// 2911.312 us; speedup vs baseline: 2.3585x; 2.3585x over previous
//
#include <hip/hip_runtime.h>
#include <cstdint>

#define BX   32
#define NN   1000
#define FF   16
#define TT   48          // HIST + FC
#define HIST 24
#define FC   24
#define HID  64
#define DEG  16
#define GCIN 18          // F + 2
#define BN   (BX*NN)     // 32000 nodes

__device__ __forceinline__ float sigf(float x)  { return 1.0f/(1.0f+__expf(-x)); }
__device__ __forceinline__ float tanhf_(float x){ return 2.0f/(1.0f+__expf(-2.0f*x)) - 1.0f; }

// ---------------- pre-pass: static part of the edge aggregation ----------------
// agg_static[t][k][node] = sum_e w_e * [y_t, X_t](src_e)[k]  for k=0..16
// Fully parallel over 24 x 32000 — hoisted out of the sequential scan.
__global__ __launch_bounds__(256, 2) void agg_pre(
    const float* __restrict__ X, const float* __restrict__ y,
    const int*   __restrict__ esrc, const float* __restrict__ ew,
    float* __restrict__ aggs)
{
    const int node = blockIdx.x*256 + threadIdx.x;   // < 32000
    const int t    = blockIdx.y;                     // 0..23
    const int b    = node / NN;
    const float* Xt = X + (size_t)(b*TT + t)*NN*FF;
    const float* yt = y + (size_t)(b*TT + t)*NN;

    float agg[17];
    #pragma unroll
    for (int i=0;i<17;i++) agg[i]=0.f;

    const int e0 = node*DEG;
    const int4*   sv = (const int4*)  (esrc + e0);
    const float4* wv = (const float4*)(ew   + e0);
    #pragma unroll
    for (int q=0;q<4;q++){
        int4   s4 = sv[q];
        float4 w4 = wv[q];
        const int   ss[4] = {s4.x, s4.y, s4.z, s4.w};
        const float ww[4] = {w4.x, w4.y, w4.z, w4.w};
        #pragma unroll
        for (int i=0;i<4;i++){
            const int sl = ss[i] - b*NN;
            const float wgt = ww[i];
            agg[0] += wgt * yt[sl];
            const float4* sr = (const float4*)(Xt + sl*FF);
            #pragma unroll
            for (int q2=0;q2<4;q2++){
                float4 v = sr[q2];
                agg[1+4*q2] += wgt*v.x; agg[2+4*q2] += wgt*v.y;
                agg[3+4*q2] += wgt*v.z; agg[4+4*q2] += wgt*v.w;
            }
        }
    }
    #pragma unroll
    for (int k=0;k<17;k++) aggs[((size_t)t*17 + k)*BN + node] = agg[k];
}

// ---------------- encoder step: xn-gather + GraphConv + GRU + out-proj --------
// block = 256 threads = 4 waves; 64 nodes/block (lane = node), wave = j-quarter
// (16 of 64 hidden outputs). grid = 500 -> 2000 waves (~2 waves/SIMD).
__global__ __launch_bounds__(256, 2) void enc_step(
    const float* __restrict__ X, const float* __restrict__ y,
    const int*   __restrict__ esrc, const float* __restrict__ ew,
    const float* __restrict__ aggs,
    const float* __restrict__ W_rel, const float* __restrict__ b_rel,
    const float* __restrict__ W_root,
    const float* __restrict__ Wih, const float* __restrict__ Whh,
    const float* __restrict__ bih, const float* __restrict__ bhh,
    const float* __restrict__ Wout, const float* __restrict__ bout,
    const float* __restrict__ h_in, float* __restrict__ h_out,
    const float* __restrict__ xn_in, float* __restrict__ xn_out,
    int t)
{
    __shared__ float cl[HID][64];    // conv exchange (stride-1 in node: conflict-free)
    __shared__ float xs[4][64];      // xn partial sums

    const int lane = threadIdx.x & 63;
    int jq = threadIdx.x >> 6;                  // 0..3 j-quarter
    jq = __builtin_amdgcn_readfirstlane(jq);    // wave-uniform -> s_load weights
    const int node = blockIdx.x*64 + lane;      // < 32000
    const int b    = node / NN;
    const int nloc = node - b*NN;

    const float* Xt = X + (size_t)(b*TT + t)*NN*FF;
    const float* yt = y + (size_t)(b*TT + t)*NN;

    // ---- own features xg = [xn, y, X] ----
    float xg[GCIN];
    xg[0] = xn_in[node];
    xg[1] = yt[nloc];
    {
        const float4* xr = (const float4*)(Xt + nloc*FF);
        #pragma unroll
        for (int q=0;q<4;q++){ float4 v = xr[q];
            xg[2+4*q]=v.x; xg[3+4*q]=v.y; xg[4+4*q]=v.z; xg[5+4*q]=v.w; }
    }

    // ---- aggregation: dynamic xn channel gathered, static channels loaded ----
    float agf[GCIN];
    {
        float a0 = 0.f;
        const int e0 = node*DEG;
        const int4*   sv = (const int4*)  (esrc + e0);
        const float4* wv = (const float4*)(ew   + e0);
        #pragma unroll
        for (int q=0;q<4;q++){
            int4   s4 = sv[q];
            float4 w4 = wv[q];
            a0 += w4.x * xn_in[s4.x];
            a0 += w4.y * xn_in[s4.y];
            a0 += w4.z * xn_in[s4.z];
            a0 += w4.w * xn_in[s4.w];
        }
        agf[0] = a0;
    }
    #pragma unroll
    for (int k=0;k<17;k++) agf[1+k] = aggs[((size_t)t*17 + k)*BN + node];

    // ---- GraphConv quarter (16 outputs per wave) -> LDS ----
    const int j0 = jq*16;
    {
        float c[16];
        #pragma unroll
        for (int j=0;j<16;j++) c[j] = b_rel[j0+j];
        #pragma unroll
        for (int k=0;k<GCIN;k++){
            const float* wr = W_rel  + k*HID + j0;
            const float* wo = W_root + k*HID + j0;
            #pragma unroll
            for (int j=0;j<16;j++) c[j] += agf[k]*wr[j] + xg[k]*wo[j];
        }
        #pragma unroll
        for (int j=0;j<16;j++) cl[j0+j][lane] = sigf(c[j]);
    }
    __syncthreads();

    float conv[HID];
    #pragma unroll
    for (int k=0;k<HID;k++) conv[k] = cl[k][lane];

    float h[HID];
    #pragma unroll
    for (int k=0;k<HID;k++) h[k] = h_in[(size_t)k*BN + node];

    // ---- GRU gates, 16 outputs per wave (dynamic j-loop, static inner dots) ----
    float xacc = 0.f;
    for (int j=0;j<16;j++){
        const int jj = j0 + j;
        const float* wr_r = Wih + (size_t) jj      *82;
        const float* wr_z = Wih + (size_t)(jj+ 64) *82;
        const float* wr_n = Wih + (size_t)(jj+128) *82;
        float ir = bih[jj], iz = bih[64+jj], in2 = bih[128+jj];
        #pragma unroll
        for (int k=0;k<GCIN;k++){
            const float xv = xg[k];
            ir += xv*wr_r[k]; iz += xv*wr_z[k]; in2 += xv*wr_n[k];
        }
        #pragma unroll
        for (int k=0;k<HID;k++){
            const float xv = conv[k];
            ir += xv*wr_r[GCIN+k]; iz += xv*wr_z[GCIN+k]; in2 += xv*wr_n[GCIN+k];
        }
        const float* wh_r = Whh + (size_t) jj      *HID;
        const float* wh_z = Whh + (size_t)(jj+ 64) *HID;
        const float* wh_n = Whh + (size_t)(jj+128) *HID;
        float hr = bhh[jj], hz = bhh[64+jj], hn2 = bhh[128+jj];
        #pragma unroll
        for (int k=0;k<HID;k++){
            const float hv = h[k];
            hr += hv*wh_r[k]; hz += hv*wh_z[k]; hn2 += hv*wh_n[k];
        }
        const float r = sigf(ir+hr);
        const float z = sigf(iz+hz);
        const float n = tanhf_(in2 + r*hn2);
        const float hold = h_in[(size_t)jj*BN + node];   // == h[jj] (L1 hit; avoids scratch)
        const float hp = (1.f - z)*n + z*hold;
        h_out[(size_t)jj*BN + node] = hp;
        xacc += hp * Wout[jj];
    }

    xs[jq][lane] = xacc;
    __syncthreads();
    if (jq == 0)
        xn_out[node] = xs[0][lane] + xs[1][lane] + xs[2][lane] + xs[3][lane] + bout[0];
}

// ---------------- decoder step: in-proj + GRU + out-proj ----------------
__global__ __launch_bounds__(256, 2) void dec_step(
    const float* __restrict__ X,
    const float* __restrict__ Win, const float* __restrict__ bin,
    const float* __restrict__ Wih, const float* __restrict__ Whh,
    const float* __restrict__ bih, const float* __restrict__ bhh,
    const float* __restrict__ Wout, const float* __restrict__ bout,
    const float* __restrict__ h_in, float* __restrict__ h_out,
    const float* __restrict__ xn_in, float* __restrict__ xn_out,
    float* __restrict__ out, int t)
{
    __shared__ float xs[4][64];

    const int lane = threadIdx.x & 63;
    int jq = threadIdx.x >> 6;
    jq = __builtin_amdgcn_readfirstlane(jq);
    const int node = blockIdx.x*64 + lane;
    const int b    = node / NN;
    const int nloc = node - b*NN;

    const float* Xt = X + (size_t)(b*TT + HIST + t)*NN*FF;

    float x4[4];
    x4[0] = xn_in[node];
    x4[1] = Xt[nloc*FF + 13];
    x4[2] = Xt[nloc*FF + 14];
    x4[3] = Xt[nloc*FF + 15];

    // xin = x4 @ Win(4x64) + bin  (computed fully by each wave; cheap)
    float xin[HID];
    #pragma unroll
    for (int j=0;j<HID;j++)
        xin[j] = bin[j] + x4[0]*Win[j] + x4[1]*Win[64+j] + x4[2]*Win[128+j] + x4[3]*Win[192+j];

    float h[HID];
    #pragma unroll
    for (int k=0;k<HID;k++) h[k] = h_in[(size_t)k*BN + node];

    const int j0 = jq*16;
    float xacc = 0.f;
    for (int j=0;j<16;j++){
        const int jj = j0 + j;
        const float* wr_r = Wih + (size_t) jj      *HID;
        const float* wr_z = Wih + (size_t)(jj+ 64) *HID;
        const float* wr_n = Wih + (size_t)(jj+128) *HID;
        float ir = bih[jj], iz = bih[64+jj], in2 = bih[128+jj];
        #pragma unroll
        for (int k=0;k<HID;k++){
            const float xv = xin[k];
            ir += xv*wr_r[k]; iz += xv*wr_z[k]; in2 += xv*wr_n[k];
        }
        const float* wh_r = Whh + (size_t) jj      *HID;
        const float* wh_z = Whh + (size_t)(jj+ 64) *HID;
        const float* wh_n = Whh + (size_t)(jj+128) *HID;
        float hr = bhh[jj], hz = bhh[64+jj], hn2 = bhh[128+jj];
        #pragma unroll
        for (int k=0;k<HID;k++){
            const float hv = h[k];
            hr += hv*wh_r[k]; hz += hv*wh_z[k]; hn2 += hv*wh_n[k];
        }
        const float r = sigf(ir+hr);
        const float z = sigf(iz+hz);
        const float n = tanhf_(in2 + r*hn2);
        const float hold = h_in[(size_t)jj*BN + node];
        const float hp = (1.f - z)*n + z*hold;
        h_out[(size_t)jj*BN + node] = hp;
        xacc += hp * Wout[jj];
    }

    xs[jq][lane] = xacc;
    __syncthreads();
    if (jq == 0){
        const float v = xs[0][lane] + xs[1][lane] + xs[2][lane] + xs[3][lane] + bout[0];
        xn_out[node] = v;
        out[(size_t)(b*FC + t)*NN + nloc] = v;
    }
}

extern "C" void kernel_launch(void* const* d_in, const int* in_sizes, int n_in,
                              void* d_out, int out_size, void* d_ws, size_t ws_size,
                              hipStream_t stream)
{
    const float* X     = (const float*)d_in[0];
    const float* y     = (const float*)d_in[1];
    const int*   ei    = (const int*)  d_in[2];   // [2][E]; row 0 = src
    const float* ew    = (const float*)d_in[3];
    const float* W_rel = (const float*)d_in[4];
    const float* b_rel = (const float*)d_in[5];
    const float* W_root= (const float*)d_in[6];
    const float* eWih  = (const float*)d_in[7];
    const float* eWhh  = (const float*)d_in[8];
    const float* ebih  = (const float*)d_in[9];
    const float* ebhh  = (const float*)d_in[10];
    const float* eWout = (const float*)d_in[11];
    const float* ebout = (const float*)d_in[12];
    const float* dWin  = (const float*)d_in[13];
    const float* dbin  = (const float*)d_in[14];
    const float* dWih  = (const float*)d_in[15];
    const float* dWhh  = (const float*)d_in[16];
    const float* dbih  = (const float*)d_in[17];
    const float* dbhh  = (const float*)d_in[18];
    const float* dWout = (const float*)d_in[19];
    const float* dbout = (const float*)d_in[20];
    float* out = (float*)d_out;

    // workspace: static agg (24*17*BN = 52.2MB) + ping-pong h (2x8.19MB) + xn (2x128KB)
    float* aggs = (float*)d_ws;
    float* h0 = aggs + (size_t)24*17*BN;
    float* h1 = h0 + (size_t)BN*HID;
    float* x0 = h1 + (size_t)BN*HID;
    float* x1 = x0 + BN;

    hipMemsetAsync(h0, 0, (size_t)BN*HID*sizeof(float), stream);
    hipMemsetAsync(x0, 0, (size_t)BN*sizeof(float), stream);

    const int* esrc = ei;  // first E entries

    // hoisted static-feature aggregation for all encoder steps (parallel, once)
    agg_pre<<<dim3(125,24), 256, 0, stream>>>(X, y, esrc, ew, aggs);

    float* hin = h0; float* hout = h1;
    float* xin = x0; float* xout = x1;

    for (int t=0; t<HIST; t++){
        enc_step<<<500, 256, 0, stream>>>(X, y, esrc, ew, aggs, W_rel, b_rel, W_root,
                                          eWih, eWhh, ebih, ebhh, eWout, ebout,
                                          hin, hout, xin, xout, t);
        float* tmp;
        tmp = hin; hin = hout; hout = tmp;
        tmp = xin; xin = xout; xout = tmp;
    }
    for (int t=0; t<FC; t++){
        dec_step<<<500, 256, 0, stream>>>(X, dWin, dbin, dWih, dWhh, dbih, dbhh,
                                          dWout, dbout, hin, hout, xin, xout, out, t);
        float* tmp;
        tmp = hin; hin = hout; hout = tmp;
        tmp = xin; xin = xout; xout = tmp;
    }
}